// Round 12
// baseline (4336.663 us; speedup 1.0000x reference)
//
#include <hip/hip_runtime.h>

#define TSTEPS 2048
#define VDIM 128
#define FDIM 512

typedef __attribute__((ext_vector_type(8))) _Float16 half8;
typedef __attribute__((ext_vector_type(4))) _Float16 half4;
typedef __attribute__((ext_vector_type(4))) float floatx4;
typedef unsigned long long u64;
typedef __attribute__((ext_vector_type(2))) unsigned long long u64x2;

// ws layout (bytes):
//   [0,512K)        WH: f16, A-frag order [chunk32][kk16][lane64][e8]
//   [1M,1M+128K)    r parity-0: [g8][kk16][lane64][e8] f16 (16KB/group)
//   [1M+128K,+256K) r parity-1: same
#define WS_WH 0
#define WS_R  (1024u * 1024u)

// Pre-swizzle W (fp32 row-major [j][k]) into A-frag order, single f16.
// A-frag (16x16x32 f16): lane l holds row (l&15), k = kk*32 + (l>>4)*8 + e.
__global__ __launch_bounds__(256) void rnn_prep(const float* __restrict__ W,
                                                _Float16* __restrict__ WH) {
  int tid = blockIdx.x * 256 + threadIdx.x;   // 32 chunks * 16 kk * 64 lanes
  int c  = tid >> 10;
  int kk = (tid >> 6) & 15;
  int l  = tid & 63;
  int j  = 16 * c + (l & 15);
  int k0 = kk * 32 + (l >> 4) * 8;
  const float* src = W + j * FDIM + k0;
  half8 vh;
#pragma unroll
  for (int e = 0; e < 8; ++e) vh[e] = (_Float16)src[e];
  *(half8*)(WH + (size_t)tid * 8) = vh;
}

// 32 WGs = 8 row-groups (g) x 4 slices (s), 512 thr = 8 waves, wave owns
// chunk c = 4w+s (features [16c,16c+16)), W resident in 64 regs.
// Protocol (proven R4/R9): tag-in-data, tau(t)=(t>>1)&1 in every f16 LSB,
// IC-coherent loads/stores, LDS share, one barrier per step.
// R12: SINGLE-POLLER — wave 0 polls ALL 16 exchange chunks in one
// uninterruptible asm block (16 x dwordx4 + vmcnt(0); the only robust
// HIP-level pattern, cf. R6/R11 failures), stages all 16KB to LDS.
// Removes the max-of-8-waves sampling term from the barrier.
__global__ void __launch_bounds__(512, 1)
rnn_main(const float* __restrict__ X, const float* __restrict__ bvec,
         const _Float16* __restrict__ WH,
         _Float16* __restrict__ rbase, float* __restrict__ out) {
  __shared__ _Float16 lds[2][8192];           // 16KB per step-parity
  const int g  = blockIdx.x & 7;
  const int s  = blockIdx.x >> 3;
  const int w  = threadIdx.x >> 6;
  const int l  = threadIdx.x & 63;
  const int lr = l & 15;                      // D col = group-local state row
  const int lg = l >> 4;
  const int c  = 4 * w + s;                   // W chunk = feats [16c,16c+16)
  const int jb = 16 * c + lg * 4;             // this lane's 4 features

  // persistent W fragments: 16 x half8 = 64 regs
  half8 wh[16];
#pragma unroll
  for (int kk = 0; kk < 16; ++kk) {
    wh[kk] = ((const half8*)WH)[(c * 16 + kk) * 64 + l];
    asm volatile("" : "+v"(wh[kk]));
  }

  const floatx4 bv = *(const floatx4*)(bvec + jb);
  const bool vis = (16 * c < 128);
  const bool diagHere = (c == g);
  const u64 TAGM = 0x0001000100010001ULL;

  // produced half4 frag offset (halves): kk*512 + (sub*16+lr)*8 + (jb&7)
  const int so = ((jb >> 5) << 9) + ((((jb >> 3) & 3) << 4) + lr) * 8 + (jb & 7);

  int budget = 4000000;

  for (int t = 0; t < TSTEPS; ++t) {
    // X row load first: dead time for waiter waves, off-path for the poller
    floatx4 xv = {0.f, 0.f, 0.f, 0.f};
    if (vis) xv = *(const floatx4*)(X + t * VDIM + jb);

    char* lp = (char*)lds[t & 1];

    if (w == 0) {
      // ---- single-poller: all 16 chunks, 16B/lane each, one asm block
      const char* rbl = (const char*)rbase + (size_t)(t & 1) * (128 * 1024)
                      + (size_t)g * 16384 + (size_t)l * 16;
      const char* p0 = rbl;
      const char* p1 = rbl + 4096;
      const char* p2 = rbl + 8192;
      const char* p3 = rbl + 12288;
      const int wantbit = (t >> 1) & 1;
      u64x2 f0, f1, f2, f3, f4, f5, f6, f7, f8, f9, f10, f11, f12, f13, f14, f15;
      for (;;) {
        asm volatile(
          "global_load_dwordx4 %0, %16, off sc0 sc1\n\t"
          "global_load_dwordx4 %1, %16, off offset:1024 sc0 sc1\n\t"
          "global_load_dwordx4 %2, %16, off offset:2048 sc0 sc1\n\t"
          "global_load_dwordx4 %3, %16, off offset:3072 sc0 sc1\n\t"
          "global_load_dwordx4 %4, %17, off sc0 sc1\n\t"
          "global_load_dwordx4 %5, %17, off offset:1024 sc0 sc1\n\t"
          "global_load_dwordx4 %6, %17, off offset:2048 sc0 sc1\n\t"
          "global_load_dwordx4 %7, %17, off offset:3072 sc0 sc1\n\t"
          "global_load_dwordx4 %8, %18, off sc0 sc1\n\t"
          "global_load_dwordx4 %9, %18, off offset:1024 sc0 sc1\n\t"
          "global_load_dwordx4 %10, %18, off offset:2048 sc0 sc1\n\t"
          "global_load_dwordx4 %11, %18, off offset:3072 sc0 sc1\n\t"
          "global_load_dwordx4 %12, %19, off sc0 sc1\n\t"
          "global_load_dwordx4 %13, %19, off offset:1024 sc0 sc1\n\t"
          "global_load_dwordx4 %14, %19, off offset:2048 sc0 sc1\n\t"
          "global_load_dwordx4 %15, %19, off offset:3072 sc0 sc1\n\t"
          "s_waitcnt vmcnt(0)"
          : "=&v"(f0), "=&v"(f1), "=&v"(f2), "=&v"(f3),
            "=&v"(f4), "=&v"(f5), "=&v"(f6), "=&v"(f7),
            "=&v"(f8), "=&v"(f9), "=&v"(f10), "=&v"(f11),
            "=&v"(f12), "=&v"(f13), "=&v"(f14), "=&v"(f15)
          : "v"(p0), "v"(p1), "v"(p2), "v"(p3)
          : "memory");
        int ok;
        if (wantbit) {
          u64 m = ((f0[0] & f0[1]) & (f1[0] & f1[1]))
                & ((f2[0] & f2[1]) & (f3[0] & f3[1]))
                & ((f4[0] & f4[1]) & (f5[0] & f5[1]))
                & ((f6[0] & f6[1]) & (f7[0] & f7[1]))
                & ((f8[0] & f8[1]) & (f9[0] & f9[1]))
                & ((f10[0] & f10[1]) & (f11[0] & f11[1]))
                & ((f12[0] & f12[1]) & (f13[0] & f13[1]))
                & ((f14[0] & f14[1]) & (f15[0] & f15[1]));
          ok = ((~m) & TAGM) == 0;
        } else {
          u64 m = ((f0[0] | f0[1]) | (f1[0] | f1[1]))
                | ((f2[0] | f2[1]) | (f3[0] | f3[1]))
                | ((f4[0] | f4[1]) | (f5[0] | f5[1]))
                | ((f6[0] | f6[1]) | (f7[0] | f7[1]))
                | ((f8[0] | f8[1]) | (f9[0] | f9[1]))
                | ((f10[0] | f10[1]) | (f11[0] | f11[1]))
                | ((f12[0] | f12[1]) | (f13[0] | f13[1]))
                | ((f14[0] | f14[1]) | (f15[0] | f15[1]));
          ok = (m & TAGM) == 0;
        }
        if (__all(ok)) break;
        if (--budget < 0) break;
      }
      // ---- stage all 16 chunks into LDS (conflict-free b128, linear)
      *(u64x2*)(lp + 0 * 1024 + l * 16) = f0;
      *(u64x2*)(lp + 1 * 1024 + l * 16) = f1;
      *(u64x2*)(lp + 2 * 1024 + l * 16) = f2;
      *(u64x2*)(lp + 3 * 1024 + l * 16) = f3;
      *(u64x2*)(lp + 4 * 1024 + l * 16) = f4;
      *(u64x2*)(lp + 5 * 1024 + l * 16) = f5;
      *(u64x2*)(lp + 6 * 1024 + l * 16) = f6;
      *(u64x2*)(lp + 7 * 1024 + l * 16) = f7;
      *(u64x2*)(lp + 8 * 1024 + l * 16) = f8;
      *(u64x2*)(lp + 9 * 1024 + l * 16) = f9;
      *(u64x2*)(lp + 10 * 1024 + l * 16) = f10;
      *(u64x2*)(lp + 11 * 1024 + l * 16) = f11;
      *(u64x2*)(lp + 12 * 1024 + l * 16) = f12;
      *(u64x2*)(lp + 13 * 1024 + l * 16) = f13;
      *(u64x2*)(lp + 14 * 1024 + l * 16) = f14;
      *(u64x2*)(lp + 15 * 1024 + l * 16) = f15;
    }
    __syncthreads();

    // ---- MFMA: D[j][i] = sum_k W[j,k] r[i,k]; 4 accumulator chains
    floatx4 a0 = {0.f,0.f,0.f,0.f}, a1 = {0.f,0.f,0.f,0.f};
    floatx4 a2 = {0.f,0.f,0.f,0.f}, a3 = {0.f,0.f,0.f,0.f};
#pragma unroll
    for (int kk = 0; kk < 16; kk += 4) {
      half8 b0 = *(const half8*)(lp + kk * 1024 + l * 16);
      half8 b1 = *(const half8*)(lp + (kk + 1) * 1024 + l * 16);
      half8 b2 = *(const half8*)(lp + (kk + 2) * 1024 + l * 16);
      half8 b3 = *(const half8*)(lp + (kk + 3) * 1024 + l * 16);
      a0 = __builtin_amdgcn_mfma_f32_16x16x32_f16(wh[kk],     b0, a0, 0, 0, 0);
      a1 = __builtin_amdgcn_mfma_f32_16x16x32_f16(wh[kk + 1], b1, a1, 0, 0, 0);
      a2 = __builtin_amdgcn_mfma_f32_16x16x32_f16(wh[kk + 2], b2, a2, 0, 0, 0);
      a3 = __builtin_amdgcn_mfma_f32_16x16x32_f16(wh[kk + 3], b3, a3, 0, 0, 0);
    }

    // ---- epilogue: combine, blend, tanh, tag, publish r(t+1)
    const bool last = (t == TSTEPS - 1);
    union { half4 h; u64 u; } pk; pk.u = 0;
#pragma unroll
    for (int v = 0; v < 4; ++v) {
      float u = (a0[v] + a1[v]) + (a2[v] + a3[v]) + bv[v];
      const bool isdiag = diagHere && (lg * 4 + v == lr);
      if (vis && !isdiag) u = 0.5f * u + 0.5f * xv[v];
      if (last) {
        if (isdiag) out[16 * g + lr] = u;     // diag of U, pre-tanh
      } else {
        float au = fabsf(u);
        float e2 = __expf(-2.0f * au);
        float th = __fdividef(1.0f - e2, 1.0f + e2);
        pk.h[v] = (_Float16)copysignf(th, u);
      }
    }

    if (!last) {
      const u64 ntag = (u64)(((t + 1) >> 1) & 1) * TAGM;
      u64 val = (pk.u & ~TAGM) | ntag;
      char* wbuf = (char*)rbase + (size_t)((t + 1) & 1) * (128 * 1024)
                 + (size_t)g * 16384;
      __hip_atomic_store((u64*)(wbuf + so * 2), val, __ATOMIC_RELAXED,
                         __HIP_MEMORY_SCOPE_AGENT);
    }
  }
}

extern "C" void kernel_launch(void* const* d_in, const int* in_sizes, int n_in,
                              void* d_out, int out_size, void* d_ws, size_t ws_size,
                              hipStream_t stream) {
  const float* X = (const float*)d_in[0];
  const float* W = (const float*)d_in[1];
  const float* b = (const float*)d_in[2];
  float* out = (float*)d_out;
  char* ws = (char*)d_ws;

  _Float16* WH = (_Float16*)(ws + WS_WH);
  _Float16* rb = (_Float16*)(ws + WS_R);

  // parity-0 r: zeros (valid r(0), tag 0).  parity-1: 0x0101 (tag=1, invalid
  // for tau(1)=0).
  hipMemsetAsync(ws + WS_R, 0x00, 128 * 1024, stream);
  hipMemsetAsync(ws + WS_R + 128 * 1024, 0x01, 128 * 1024, stream);
  rnn_prep<<<128, 256, 0, stream>>>(W, WH);
  rnn_main<<<32, 512, 0, stream>>>(X, b, WH, rb, out);
}

// Round 13
// 3625.415 us; speedup vs baseline: 1.1962x; 1.1962x over previous
//
#include <hip/hip_runtime.h>

#define TSTEPS 2048
#define VDIM 128
#define FDIM 512

typedef __attribute__((ext_vector_type(8))) _Float16 half8;
typedef __attribute__((ext_vector_type(4))) _Float16 half4;
typedef __attribute__((ext_vector_type(4))) float floatx4;
typedef unsigned long long u64;
typedef __attribute__((ext_vector_type(2))) unsigned long long u64x2;

// ws layout (bytes):
//   [0,512K)        WH: f16, A-frag order [chunk32][kk16][lane64][e8]
//   [1M,1M+128K)    r parity-0: [g8][kk16][lane64][e8] f16 (16KB/group)
//   [1M+128K,+256K) r parity-1: same
#define WS_WH 0
#define WS_R  (1024u * 1024u)

// Pre-swizzle W (fp32 row-major [j][k]) into A-frag order, single f16.
// A-frag (16x16x32 f16): lane l holds row (l&15), k = kk*32 + (l>>4)*8 + e.
__global__ __launch_bounds__(256) void rnn_prep(const float* __restrict__ W,
                                                _Float16* __restrict__ WH) {
  int tid = blockIdx.x * 256 + threadIdx.x;   // 32 chunks * 16 kk * 64 lanes
  int c  = tid >> 10;
  int kk = (tid >> 6) & 15;
  int l  = tid & 63;
  int j  = 16 * c + (l & 15);
  int k0 = kk * 32 + (l >> 4) * 8;
  const float* src = W + j * FDIM + k0;
  half8 vh;
#pragma unroll
  for (int e = 0; e < 8; ++e) vh[e] = (_Float16)src[e];
  *(half8*)(WH + (size_t)tid * 8) = vh;
}

// 32 WGs = 8 row-groups (g) x 4 slices (s), 256 thr = 4 WAVES (R13: was 8).
// Wave w owns feature chunks c0=8w+s, c1=8w+4+s (32 features, W=128 regs).
// Rationale: every wave must read the ENTIRE 16KB r-tile from LDS for its
// B-frags (shared across its features), so per-CU LDS volume = waves x 16KB.
// 4 waves halves the post-barrier LDS-read phase (~770 cy) at the cost of a
// 2x epilogue (~+120 cy).  Protocol unchanged (proven R4/R9): tag-in-data,
// tau(t)=(t>>1)&1 in every f16 LSB, single-asm-block poll (loads+vmcnt(0)),
// LDS share, one barrier, IC write-through stores.
__global__ void __launch_bounds__(256, 1)
rnn_main(const float* __restrict__ X, const float* __restrict__ bvec,
         const _Float16* __restrict__ WH,
         _Float16* __restrict__ rbase, float* __restrict__ out) {
  __shared__ _Float16 lds[2][8192];           // 16KB per step-parity
  const int g  = blockIdx.x & 7;
  const int s  = blockIdx.x >> 3;
  const int w  = threadIdx.x >> 6;            // 0..3
  const int l  = threadIdx.x & 63;
  const int lr = l & 15;                      // D col = group-local state row
  const int lg = l >> 4;
  const int c0 = 8 * w + s;                   // feature chunks [16c,16c+16)
  const int c1 = 8 * w + 4 + s;
  const int jb0 = 16 * c0 + lg * 4;           // lane's 4 features per chunk
  const int jb1 = 16 * c1 + lg * 4;

  // persistent W fragments: 2 chunks x 16 kk = 128 regs
  half8 wh0[16], wh1[16];
#pragma unroll
  for (int kk = 0; kk < 16; ++kk) {
    wh0[kk] = ((const half8*)WH)[(c0 * 16 + kk) * 64 + l];
    wh1[kk] = ((const half8*)WH)[(c1 * 16 + kk) * 64 + l];
    asm volatile("" : "+v"(wh0[kk]), "+v"(wh1[kk]));
  }

  const floatx4 bv0 = *(const floatx4*)(bvec + jb0);
  const floatx4 bv1 = *(const floatx4*)(bvec + jb1);
  const bool vis0 = (c0 < 8), vis1 = (c1 < 8);
  const bool diag0 = (c0 == g), diag1 = (c1 == g);
  const u64 TAGM = 0x0001000100010001ULL;

  // poll region: wave w owns kk-chunks 4w..4w+3; 16B/lane each
  const int pcB = (4 * w) * 1024 + l * 16;
  // produced half4 frag offsets (halves)
  const int so0 = ((jb0 >> 5) << 9) + ((((jb0 >> 3) & 3) << 4) + lr) * 8 + (jb0 & 7);
  const int so1 = ((jb1 >> 5) << 9) + ((((jb1 >> 3) & 3) << 4) + lr) * 8 + (jb1 & 7);

  int budget = 4000000;

  for (int t = 0; t < TSTEPS; ++t) {
    // X rows: issued pre-poll (drained by first poll iter; data not yet
    // visible then anyway, so this is free)
    floatx4 xv0 = {0.f,0.f,0.f,0.f}, xv1 = {0.f,0.f,0.f,0.f};
    if (vis0) xv0 = *(const floatx4*)(X + t * VDIM + jb0);
    if (vis1) xv1 = *(const floatx4*)(X + t * VDIM + jb1);

    // ---- poll own 4 kk-chunks: ONE asm block (loads + vmcnt(0)), the only
    // robust HIP-level pattern (R6/R11 lessons)
    const char* p0 = (const char*)rbase + (size_t)(t & 1) * (128 * 1024)
                   + (size_t)g * 16384 + pcB;
    const int wantbit = (t >> 1) & 1;
    u64x2 f0, f1, f2, f3;
    for (;;) {
      asm volatile(
        "global_load_dwordx4 %0, %4, off sc0 sc1\n\t"
        "global_load_dwordx4 %1, %4, off offset:1024 sc0 sc1\n\t"
        "global_load_dwordx4 %2, %4, off offset:2048 sc0 sc1\n\t"
        "global_load_dwordx4 %3, %4, off offset:3072 sc0 sc1\n\t"
        "s_waitcnt vmcnt(0)"
        : "=&v"(f0), "=&v"(f1), "=&v"(f2), "=&v"(f3)
        : "v"(p0) : "memory");
      int ok;
      if (wantbit) {
        u64 m = (f0[0] & f0[1]) & (f1[0] & f1[1])
              & (f2[0] & f2[1]) & (f3[0] & f3[1]);
        ok = ((~m) & TAGM) == 0;
      } else {
        u64 m = (f0[0] | f0[1]) | (f1[0] | f1[1])
              | (f2[0] | f2[1]) | (f3[0] | f3[1]);
        ok = (m & TAGM) == 0;
      }
      if (__all(ok)) break;
      if (--budget < 0) break;
    }

    // ---- stage own 4 chunks into LDS (linear frag order, conflict-free)
    char* lp = (char*)lds[t & 1];
    *(u64x2*)(lp + pcB)        = f0;
    *(u64x2*)(lp + pcB + 1024) = f1;
    *(u64x2*)(lp + pcB + 2048) = f2;
    *(u64x2*)(lp + pcB + 3072) = f3;
    __syncthreads();

    // ---- MFMA: D[j][i] = sum_k W[j,k] r[i,k]; 2 chains (one per chunk)
    floatx4 a0 = {0.f,0.f,0.f,0.f}, a1 = {0.f,0.f,0.f,0.f};
#pragma unroll
    for (int kk = 0; kk < 16; ++kk) {
      half8 b = *(const half8*)(lp + kk * 1024 + l * 16);
      a0 = __builtin_amdgcn_mfma_f32_16x16x32_f16(wh0[kk], b, a0, 0, 0, 0);
      a1 = __builtin_amdgcn_mfma_f32_16x16x32_f16(wh1[kk], b, a1, 0, 0, 0);
    }

    // ---- epilogue: combine, blend, tanh, tag, publish r(t+1), both chunks
    const bool last = (t == TSTEPS - 1);
    union { half4 h; u64 u; } pk0, pk1; pk0.u = 0; pk1.u = 0;
#pragma unroll
    for (int v = 0; v < 4; ++v) {
      float u0 = a0[v] + bv0[v];
      float u1 = a1[v] + bv1[v];
      const bool d0 = diag0 && (lg * 4 + v == lr);
      const bool d1 = diag1 && (lg * 4 + v == lr);
      if (vis0 && !d0) u0 = 0.5f * u0 + 0.5f * xv0[v];
      if (vis1 && !d1) u1 = 0.5f * u1 + 0.5f * xv1[v];
      if (last) {
        if (d0) out[16 * g + lr] = u0;        // diag of U, pre-tanh
        if (d1) out[16 * g + lr] = u1;
      } else {
        float au0 = fabsf(u0), au1 = fabsf(u1);
        float e0 = __expf(-2.0f * au0), e1 = __expf(-2.0f * au1);
        float t0 = __fdividef(1.0f - e0, 1.0f + e0);
        float t1 = __fdividef(1.0f - e1, 1.0f + e1);
        pk0.h[v] = (_Float16)copysignf(t0, u0);
        pk1.h[v] = (_Float16)copysignf(t1, u1);
      }
    }

    if (!last) {
      const u64 ntag = (u64)(((t + 1) >> 1) & 1) * TAGM;
      u64 val0 = (pk0.u & ~TAGM) | ntag;
      u64 val1 = (pk1.u & ~TAGM) | ntag;
      char* wbuf = (char*)rbase + (size_t)((t + 1) & 1) * (128 * 1024)
                 + (size_t)g * 16384;
      __hip_atomic_store((u64*)(wbuf + so0 * 2), val0, __ATOMIC_RELAXED,
                         __HIP_MEMORY_SCOPE_AGENT);
      __hip_atomic_store((u64*)(wbuf + so1 * 2), val1, __ATOMIC_RELAXED,
                         __HIP_MEMORY_SCOPE_AGENT);
    }
  }
}

extern "C" void kernel_launch(void* const* d_in, const int* in_sizes, int n_in,
                              void* d_out, int out_size, void* d_ws, size_t ws_size,
                              hipStream_t stream) {
  const float* X = (const float*)d_in[0];
  const float* W = (const float*)d_in[1];
  const float* b = (const float*)d_in[2];
  float* out = (float*)d_out;
  char* ws = (char*)d_ws;

  _Float16* WH = (_Float16*)(ws + WS_WH);
  _Float16* rb = (_Float16*)(ws + WS_R);

  // parity-0 r: zeros (valid r(0), tag 0).  parity-1: 0x0101 (tag=1, invalid
  // for tau(1)=0).
  hipMemsetAsync(ws + WS_R, 0x00, 128 * 1024, stream);
  hipMemsetAsync(ws + WS_R + 128 * 1024, 0x01, 128 * 1024, stream);
  rnn_prep<<<128, 256, 0, stream>>>(W, WH);
  rnn_main<<<32, 256, 0, stream>>>(X, b, WH, rb, out);
}